// Round 13
// baseline (355.524 us; speedup 1.0000x reference)
//
#include <hip/hip_runtime.h>

// db4 DWT, mode='symmetric', matching the JAX reference exactly:
//   cA[k] = sum_t x[reflect(2k+t-6)] * w[t]
//   cD[k] = sum_t x[reflect(2k+t-6)] * ((t&1) ? -w[7-t] : +w[7-t])
//   reflect: g<0 -> -1-g ; g>=N -> 2N-1-g ;  K = (N+7)/2
//   outputs: cA (B,K) || cD (B,K) || x3 (B,8) passthrough
//
// R13: WIDTH-wise software pipelining. R8's loop-carried rotation was defeated
// by register coalescing (VGPR stayed 24 -> compiler reused the same regs and
// inserted vmcnt(0) before compute). Here each thread processes 3 INDEPENDENT
// pair-groups in straight-line code: all 9 float4 loads are live at once (no
// loop-carried WAR), so the compiler must hoist them -> 3x MLP per wave.
// Loads stay lane-dense (group g: thread t loads float4s {p-2,p-1,p},
// p = blk*768 + g*256 + t, consecutive across lanes).
// Stores: nontemporal float2 (output never re-read; avoid evicting warm input
// from LLC). Row-parity shift keeps store addresses 8B-aligned for all rows.

typedef float v2f __attribute__((ext_vector_type(2)));

#define GROUPS 3
#define PAIRS_PER_BLOCK (GROUPS * 256)

__device__ __forceinline__ constexpr float WLc(int t) {
    constexpr float w[8] = {
        0.23037781330885523f,  0.7148465705525415f,  0.6308807679295904f,
       -0.02798376941698385f, -0.18703481171888114f, 0.030841381835986965f,
        0.032883011666982945f,-0.010597401784997278f };
    return w[t];
}
__device__ __forceinline__ constexpr float WHc(int t) {
    return (t & 1) ? -WLc(7 - t) : WLc(7 - t);
}

__global__ __launch_bounds__(256) void dwt_db4_kernel(
    const float* __restrict__ x, float* __restrict__ out,
    int B, int N, int K, int P, int bpr)
{
    const int blk = blockIdx.x;
    const int row = blk / bpr;
    const int tb  = blk - row * bpr;
    const int tid = threadIdx.x;
    const int s   = row & 1;               // K odd: row*K parity == row parity
    const float* __restrict__ xr = x + (long long)row * N;
    const long long BK = (long long)B * K;
    const long long rowbase = (long long)row * K;

    // ---- phase 1: issue ALL groups' loads (9 independent float4 loads) ----
    int p[GROUPS], gb[GROUPS];
    float f[GROUPS][12];
    #pragma unroll
    for (int g = 0; g < GROUPS; ++g) {
        p[g]  = tb * PAIRS_PER_BLOCK + (g << 8) + tid;   // pair index in row
        gb[g] = 4 * p[g] - 8;                            // window base, 16B-aligned
        const int cb = min(max(gb[g], 0), N - 12);       // clamped: always legal
        const float4* sp = reinterpret_cast<const float4*>(xr + cb);
        float4 v0 = sp[0], v1 = sp[1], v2 = sp[2];       // lane-consecutive
        f[g][0]=v0.x; f[g][1]=v0.y; f[g][2] =v0.z; f[g][3] =v0.w;
        f[g][4]=v1.x; f[g][5]=v1.y; f[g][6] =v1.z; f[g][7] =v1.w;
        f[g][8]=v2.x; f[g][9]=v2.y; f[g][10]=v2.z; f[g][11]=v2.w;
    }

    // ---- phase 2: per-group edge fixup + compute + nt store ----
    #pragma unroll
    for (int g = 0; g < GROUPS; ++g) {
        if (p[g] >= P) continue;                         // beyond row's pairs
        if (gb[g] < 0 || gb[g] > N - 12) {
            // row-edge lanes only (~4 per row per group boundary): reflect gather
            #pragma unroll
            for (int m = 0; m < 12; ++m) {
                int q = gb[g] + m;
                if (q < 0) q = -1 - q;
                if (q >= N) q = 2 * N - 1 - q;
                f[g][m] = xr[q];
            }
        }

        // even rows (s=0): pair (2p,2p+1) uses f[2..9], f[4..11]
        // odd  rows (s=1): pair (2p-1,2p) uses f[0..7], f[2..9]
        const int off = 2 - 2 * s;
        float a0 = f[g][off]     * WLc(0), d0 = f[g][off]     * WHc(0);
        float a1 = f[g][off + 2] * WLc(0), d1 = f[g][off + 2] * WHc(0);
        #pragma unroll
        for (int t = 1; t < 8; ++t) {
            a0 = fmaf(f[g][off + t],     WLc(t), a0);
            d0 = fmaf(f[g][off + t],     WHc(t), d0);
            a1 = fmaf(f[g][off + 2 + t], WLc(t), a1);
            d1 = fmaf(f[g][off + 2 + t], WHc(t), d1);
        }

        const int k0 = 2 * p[g] - s;                     // -1 only for p=0 odd rows
        float* __restrict__ oA = out + rowbase + k0;
        float* __restrict__ oD = oA + BK;
        if (k0 >= 0 && k0 + 1 < K) {
            v2f va = {a0, a1}, vd = {d0, d1};            // rowbase+k0 even -> 8B-aligned
            __builtin_nontemporal_store(va, reinterpret_cast<v2f*>(oA));
            __builtin_nontemporal_store(vd, reinterpret_cast<v2f*>(oD));
        } else if (k0 < 0) {                             // odd row, first pair: k=0 only
            oA[1] = a1; oD[1] = d1;
        } else if (k0 < K) {                             // even row, last pair: k=K-1 only
            oA[0] = a0; oD[0] = d0;
        }
    }
}

__global__ void copy_tail_kernel(const float* __restrict__ src,
                                 float* __restrict__ dst, int n)
{
    int i = blockIdx.x * blockDim.x + threadIdx.x;
    if (i < n) dst[i] = src[i];
}

extern "C" void kernel_launch(void* const* d_in, const int* in_sizes, int n_in,
                              void* d_out, int out_size, void* d_ws, size_t ws_size,
                              hipStream_t stream) {
    const float* x1 = (const float*)d_in[0];
    // d_in[1] = x2: unused by the reference
    const float* x3 = (const float*)d_in[2];
    float* out = (float*)d_out;

    const int B = in_sizes[2] / 8;          // 512
    const int N = in_sizes[0] / B;          // 65536
    const int K = (N + 7) / 2;              // 32771
    const int P = K / 2 + 1;                // 16386 pairs per row (both parities)
    const int bpr = (P + PAIRS_PER_BLOCK - 1) / PAIRS_PER_BLOCK;   // 22
    const int grid = B * bpr;               // 11264 blocks

    dwt_db4_kernel<<<grid, 256, 0, stream>>>(x1, out, B, N, K, P, bpr);

    const int n3 = in_sizes[2];             // 4096
    copy_tail_kernel<<<(n3 + 255) / 256, 256, 0, stream>>>(
        x3, out + 2LL * B * K, n3);
}